// Round 8
// baseline (570.045 us; speedup 1.0000x reference)
//
#include <hip/hip_runtime.h>
#include <hip/hip_bf16.h>
#include <math.h>

#define N_NODES 40000
#define NE      640000
#define FIN     33
#define H       128
#define COUT    3
#define NLAYERS 8
#define ALPHA   0.1f
#define THETA   0.5f
#define SCAN_B  157            // ceil(N_NODES / 256)

typedef __bf16 bf16x8 __attribute__((ext_vector_type(8)));
typedef float  f32x4  __attribute__((ext_vector_type(4)));

__device__ inline unsigned short f2bf(float f) {
    __hip_bfloat16 b = __float2bfloat16(f);
    return *(unsigned short*)&b;
}
__device__ inline float bf2f(unsigned short u) {
    __hip_bfloat16 b = *(__hip_bfloat16*)&u;
    return __bfloat162float(b);
}

// ---------------- CSR build ----------------
__global__ void k_hist(const int* __restrict__ row, int* __restrict__ counts) {
    int e = blockIdx.x * blockDim.x + threadIdx.x;
    if (e < NE) atomicAdd(&counts[row[e]], 1);
}

__global__ __launch_bounds__(256) void k_scan1(const int* __restrict__ counts,
                        int* __restrict__ row_ptr, int* __restrict__ partial) {
    __shared__ int s[256];
    int t = threadIdx.x, i = blockIdx.x * 256 + t;
    int v = (i < N_NODES) ? counts[i] : 0;
    s[t] = v;
    __syncthreads();
    for (int off = 1; off < 256; off <<= 1) {
        int x = s[t];
        int add = (t >= off) ? s[t - off] : 0;
        __syncthreads();
        s[t] = x + add;
        __syncthreads();
    }
    if (i < N_NODES) row_ptr[i] = s[t] - v;      // exclusive within block
    if (t == 255) partial[blockIdx.x] = s[255];
}

__global__ __launch_bounds__(256) void k_scan2(int* __restrict__ partial) {
    __shared__ int s[256];
    int t = threadIdx.x;
    int v = (t < SCAN_B) ? partial[t] : 0;
    s[t] = v;
    __syncthreads();
    for (int off = 1; off < 256; off <<= 1) {
        int x = s[t];
        int add = (t >= off) ? s[t - off] : 0;
        __syncthreads();
        s[t] = x + add;
        __syncthreads();
    }
    if (t < SCAN_B) partial[t] = s[t] - v;       // exclusive base
}

__global__ __launch_bounds__(256) void k_scan3(const int* __restrict__ partial,
                        int* __restrict__ row_ptr, int* __restrict__ cursor) {
    int t = threadIdx.x, i = blockIdx.x * 256 + t;
    if (i < N_NODES) {
        int v = row_ptr[i] + partial[blockIdx.x];
        row_ptr[i] = v;
        cursor[i] = v;
    }
    if (i == 0) row_ptr[N_NODES] = NE;
}

// pack edge -> 4 bytes: [bf16 weight | 16-bit col]   (N=40000 < 65536)
__global__ void k_scatter(const int* __restrict__ row, const int* __restrict__ col,
                          const float* __restrict__ w, int* __restrict__ cursor,
                          unsigned int* __restrict__ ep4) {
    int e = blockIdx.x * blockDim.x + threadIdx.x;
    if (e < NE) {
        int r = row[e];
        int pos = atomicAdd(&cursor[r], 1);
        unsigned int wb = f2bf((1.0f - ALPHA) * w[e]);
        ep4[pos] = (wb << 16) | (unsigned int)col[e];
    }
}

// ---- Wtbf[l][j][k] = bf16(W[l][k][j])  (B operand for MFMA, row = output col)
__global__ __launch_bounds__(256) void k_wprep(const float* __restrict__ W,
                        unsigned short* __restrict__ Wtbf) {
    int idx = blockIdx.x * 256 + threadIdx.x;     // 8*128*128 = 131072
    int l = idx >> 14;
    int rem = idx & 16383;
    int k = rem >> 7, j = rem & 127;
    Wtbf[l * 16384 + j * 128 + k] = f2bf(W[idx]); // W[idx] = W[l][k][j], coalesced read
}

// ---- x0 = relu(x @ W_in^T + b_in); h = x0 (fp32); x0bf, hbf = bf16(x0) ----
__global__ __launch_bounds__(256) void k_xin(const float* __restrict__ x,
                      const float* __restrict__ Win, const float* __restrict__ bin,
                      float* __restrict__ h, unsigned short* __restrict__ x0bf,
                      unsigned short* __restrict__ hbf) {
    __shared__ float sW[H * FIN];      // 16.9 KB
    __shared__ float sx[16][FIN];      // 2.1 KB
    int t = threadIdx.x;
    for (int i = t; i < H * FIN; i += 256) sW[i] = Win[i];
    int n0 = blockIdx.x * 16;
    for (int i = t; i < 16 * FIN; i += 256)
        sx[i / FIN][i % FIN] = x[(size_t)(n0 + i / FIN) * FIN + (i % FIN)];
    __syncthreads();
    int f = t % H;
    int l0 = t / H;                    // 0..1
    float bv = bin[f];
    for (int lo = l0; lo < 16; lo += 2) {
        float acc = bv;
        #pragma unroll
        for (int k = 0; k < FIN; k++) acc += sx[lo][k] * sW[f * FIN + k];
        acc = fmaxf(acc, 0.f);
        size_t idx = (size_t)(n0 + lo) * H + f;
        h[idx] = acc;
        unsigned short b = f2bf(acc);
        x0bf[idx] = b;
        hbf[idx] = b;
    }
}

// ---- xx = A@hbf + alpha*x0bf -> bf16; wave/row, half-wave edge pairing ----
// lanes 0-31 handle edge i, lanes 32-63 edge i+1: one dwordx2 (8B/lane) gather
// fetches TWO 256B rows -> 0.5 VMEM/edge. Edge records fetched cooperatively
// (1 load / 64 edges) and broadcast via shfl. 8 paired chains (16 edges in
// flight = 8 outstanding dwordx2 per wave).
#define PAIR(ii, CH) { \
    unsigned int u = __shfl(ue, (ii) + half); \
    int col = (int)(u & 0xffffu); float w = bf2f((unsigned short)(u >> 16)); \
    ushort4 v = *(const ushort4*)(hbf + (size_t)col * H + (l32 << 2)); \
    CH[0] += w * bf2f(v.x); CH[1] += w * bf2f(v.y); \
    CH[2] += w * bf2f(v.z); CH[3] += w * bf2f(v.w); }

#define SING(ii, CH) { \
    unsigned int us = __shfl(ue, (ii)); \
    unsigned int u = half ? 0u : us; \
    int col = (int)(u & 0xffffu); float w = bf2f((unsigned short)(u >> 16)); \
    ushort4 v = *(const ushort4*)(hbf + (size_t)col * H + (l32 << 2)); \
    CH[0] += w * bf2f(v.x); CH[1] += w * bf2f(v.y); \
    CH[2] += w * bf2f(v.z); CH[3] += w * bf2f(v.w); }

__global__ __launch_bounds__(256) void k_spmm(const int* __restrict__ row_ptr,
                       const unsigned int* __restrict__ ep4,
                       const unsigned short* __restrict__ hbf,
                       const unsigned short* __restrict__ x0bf,
                       unsigned short* __restrict__ xxbf) {
    int wave = (blockIdx.x * blockDim.x + threadIdx.x) >> 6;
    int lane = threadIdx.x & 63;
    if (wave >= N_NODES) return;
    int beg = row_ptr[wave], end = row_ptr[wave + 1];
    int deg = end - beg;
    int half = lane >> 5, l32 = lane & 31;

    float c0[4] = {0,0,0,0}, c1[4] = {0,0,0,0}, c2[4] = {0,0,0,0}, c3[4] = {0,0,0,0};
    float c4[4] = {0,0,0,0}, c5[4] = {0,0,0,0}, c6[4] = {0,0,0,0}, c7[4] = {0,0,0,0};

    for (int base = 0; base < deg; base += 64) {
        int rem = deg - base; if (rem > 64) rem = 64;
        unsigned int ue = (lane < rem) ? ep4[beg + base + lane] : 0u;
        int i = 0;
        for (; i + 16 <= rem; i += 16) {
            PAIR(i + 0,  c0) PAIR(i + 2,  c1) PAIR(i + 4,  c2) PAIR(i + 6,  c3)
            PAIR(i + 8,  c4) PAIR(i + 10, c5) PAIR(i + 12, c6) PAIR(i + 14, c7)
        }
        for (; i + 4 <= rem; i += 4) {
            PAIR(i + 0, c0) PAIR(i + 2, c1)
        }
        if (i + 2 <= rem) { PAIR(i, c2) i += 2; }
        if (i < rem)      { SING(i, c3) }
    }

    float a[4];
    #pragma unroll
    for (int k = 0; k < 4; k++) {
        a[k] = ((c0[k] + c1[k]) + (c2[k] + c3[k]))
             + ((c4[k] + c5[k]) + (c6[k] + c7[k]));
        a[k] += __shfl_xor(a[k], 32);              // cross-half reduce
    }

    if (half == 0) {
        ushort4 xv = *(const ushort4*)(x0bf + (size_t)wave * H + (l32 << 2));
        ushort4 o;
        o.x = f2bf(a[0] + ALPHA * bf2f(xv.x));
        o.y = f2bf(a[1] + ALPHA * bf2f(xv.y));
        o.z = f2bf(a[2] + ALPHA * bf2f(xv.z));
        o.w = f2bf(a[3] + ALPHA * bf2f(xv.w));
        *(ushort4*)(xxbf + (size_t)wave * H + (l32 << 2)) = o;
    }
}

// ---- MFMA GEMM + epilogue: h += relu((1-b)*xx + b*(xx@W)); hbf = bf16(h) --
// block = 4 waves, 64 rows; wave = 16 rows x 128 cols (8 16x16 acc tiles).
// do_out: also emit out = h @ W_out^T + b_out (last layer; fp32 hv in regs).
__global__ __launch_bounds__(256) void k_gemm(const unsigned short* __restrict__ xxbf,
                       float* __restrict__ h, const unsigned short* __restrict__ Wtbf,
                       unsigned short* __restrict__ hbf, float beta,
                       const float* __restrict__ Wout, const float* __restrict__ bout,
                       float* __restrict__ out, int do_out) {
    int t = threadIdx.x;
    int wv = t >> 6, lane = t & 63;
    int quad = lane >> 4, l16 = lane & 15;
    int rbase = blockIdx.x * 64 + wv * 16;

    f32x4 acc[8];
    #pragma unroll
    for (int j = 0; j < 8; j++) acc[j] = (f32x4){0.f, 0.f, 0.f, 0.f};

    #pragma unroll
    for (int k0 = 0; k0 < 4; k0++) {
        bf16x8 av = *(const bf16x8*)(xxbf + (size_t)(rbase + l16) * H + k0 * 32 + quad * 8);
        #pragma unroll
        for (int j = 0; j < 8; j++) {
            bf16x8 bv = *(const bf16x8*)(Wtbf + (size_t)(j * 16 + l16) * H + k0 * 32 + quad * 8);
            acc[j] = __builtin_amdgcn_mfma_f32_16x16x32_bf16(av, bv, acc[j], 0, 0, 0);
        }
    }

    float omb = 1.f - beta;
    float po[4][3];
    #pragma unroll
    for (int r = 0; r < 4; r++) { po[r][0] = 0.f; po[r][1] = 0.f; po[r][2] = 0.f; }

    #pragma unroll
    for (int j = 0; j < 8; j++) {
        int col = j * 16 + l16;
        float w0 = 0.f, w1 = 0.f, w2 = 0.f;
        if (do_out) { w0 = Wout[col]; w1 = Wout[H + col]; w2 = Wout[2 * H + col]; }
        #pragma unroll
        for (int r = 0; r < 4; r++) {
            int row = rbase + quad * 4 + r;        // C/D: row = quad*4 + reg
            size_t idx = (size_t)row * H + col;
            float sk = bf2f(xxbf[idx]);            // skip term (bf16)
            float o = omb * sk + beta * acc[j][r];
            float hv = h[idx] + fmaxf(o, 0.f);
            h[idx] = hv;
            hbf[idx] = f2bf(hv);
            po[r][0] += hv * w0; po[r][1] += hv * w1; po[r][2] += hv * w2;
        }
    }

    if (do_out) {
        // reduce across the 16 lanes of each quad (xor strides stay in-quad)
        #pragma unroll
        for (int off = 1; off < 16; off <<= 1) {
            #pragma unroll
            for (int r = 0; r < 4; r++) {
                po[r][0] += __shfl_xor(po[r][0], off);
                po[r][1] += __shfl_xor(po[r][1], off);
                po[r][2] += __shfl_xor(po[r][2], off);
            }
        }
        if (l16 == 0) {
            #pragma unroll
            for (int r = 0; r < 4; r++) {
                int row = rbase + quad * 4 + r;
                out[(size_t)row * 3 + 0] = po[r][0] + bout[0];
                out[(size_t)row * 3 + 1] = po[r][1] + bout[1];
                out[(size_t)row * 3 + 2] = po[r][2] + bout[2];
            }
        }
    }
}

extern "C" void kernel_launch(void* const* d_in, const int* in_sizes, int n_in,
                              void* d_out, int out_size, void* d_ws, size_t ws_size,
                              hipStream_t stream) {
    const float* x     = (const float*)d_in[0];
    const int*   erow  = (const int*)  d_in[1];
    const int*   ecol  = (const int*)  d_in[2];
    const float* ew    = (const float*)d_in[3];
    const float* Win   = (const float*)d_in[4];
    const float* bin   = (const float*)d_in[5];
    const float* Wout  = (const float*)d_in[6];
    const float* bout  = (const float*)d_in[7];
    const float* Wconv = (const float*)d_in[8];
    float* out = (float*)d_out;

    char* ws = (char*)d_ws;
    const size_t NHf = (size_t)N_NODES * H * sizeof(float);           // 20,480,000
    const size_t NHb = (size_t)N_NODES * H * sizeof(unsigned short);  // 10,240,000
    float*          h     = (float*)(ws);
    unsigned short* xxbf  = (unsigned short*)(ws + NHf);
    unsigned short* x0bf  = (unsigned short*)(ws + NHf + NHb);
    unsigned short* hbf   = (unsigned short*)(ws + NHf + 2 * NHb);
    char* p = ws + NHf + 3 * NHb;
    unsigned short* Wtbf  = (unsigned short*)p;  p += 8 * H * H * 2;  // 262,144
    int*  counts  = (int*) p;  p += 160256;
    int*  row_ptr = (int*) p;  p += 160256;
    int*  cursor  = (int*) p;  p += 160256;
    int*  partial = (int*) p;  p += 1024;
    unsigned int* ep4 = (unsigned int*)p;        // NE * 4 bytes

    // CSR build (inputs restored pristine before every call)
    hipMemsetAsync(counts, 0, (size_t)N_NODES * 4, stream);
    k_hist   <<<NE / 256, 256, 0, stream>>>(erow, counts);
    k_scan1  <<<SCAN_B,   256, 0, stream>>>(counts, row_ptr, partial);
    k_scan2  <<<1,        256, 0, stream>>>(partial);
    k_scan3  <<<SCAN_B,   256, 0, stream>>>(partial, row_ptr, cursor);
    k_scatter<<<NE / 256, 256, 0, stream>>>(erow, ecol, ew, cursor, ep4);

    // weight prep + input projection
    k_wprep<<<8 * H * H / 256, 256, 0, stream>>>(Wconv, Wtbf);
    k_xin  <<<N_NODES / 16,    256, 0, stream>>>(x, Win, bin, h, x0bf, hbf);

    // layers: spmm -> xxbf (bf16); gemm: h += relu(...), refresh hbf;
    // last layer's gemm also emits the output projection.
    for (int l = 0; l < NLAYERS; l++) {
        float beta = logf(THETA / (float)(l + 1) + 1.0f);
        k_spmm<<<N_NODES / 4,  256, 0, stream>>>(row_ptr, ep4, hbf, x0bf, xxbf);
        k_gemm<<<N_NODES / 64, 256, 0, stream>>>(xxbf, h, Wtbf + (size_t)l * H * H,
                                                 hbf, beta, Wout, bout, out,
                                                 (l == NLAYERS - 1) ? 1 : 0);
    }
}